// Round 3
// baseline (240.865 us; speedup 1.0000x reference)
//
#include <hip/hip_runtime.h>
#include <stdint.h>

#define CUBE_LEN   512
#define EQU_H      1024
#define EQU_W      2048
#define EQU_COUNT  4
#define CHANNELS   3

typedef float f32x2 __attribute__((ext_vector_type(2)));

// One thread per equirect pixel. Bilinear taps re-parameterized so
// x1 = x0+1, y1 = y0+1 always: the 4 taps of each (e,c) image are two
// ADJACENT float pairs, rows 2048 bytes apart -> 2x global_load_dwordx2
// with imm offset 0 / 2048 per image. All 24 loads + the single
// s_waitcnt live in ONE asm block (round-8: named scalar SSA outputs,
// SGPR image bases) so the full batch is in flight per wave.
//
// Round-9: 90us vs 25us traffic roofline. Little's-law says only ~1
// wave-batch of requests in flight per CU -> latency-bound on ~600cy
// Infinity-Cache hits (per-XCD L2=4MB vs 75MB working set; round-robin
// block->XCD mapping gives every XCD the whole input with no locality).
// Fix: bijective chunked XCD swizzle (8192%8==0) - XCD k owns a
// contiguous 128-row equirect band; consecutive blocks per XCD slide a
// ~2-row cube strip (~1-2MB) through L2 -> gathers become ~200cy L2 hits.
__global__ __launch_bounds__(256, 1) void cube2equirec_kernel(
    const float* __restrict__ x,
    const float* __restrict__ uv,
    const int*   __restrict__ face,
    float*       __restrict__ out)
{
    const int HW  = EQU_H * EQU_W;          // 1 << 21

    // ---- XCD-aware chunked swizzle: 8192 blocks, 8 XCDs, 1024/chunk ----
    const int bid  = blockIdx.x;
    const int sbid = (bid & 7) * 1024 + (bid >> 3);
    const int idx  = sbid * blockDim.x + threadIdx.x;
    if (idx >= HW) return;

    const float2 uvv = ((const float2*)uv)[idx];
    const float u = uvv.x;
    const float v = uvv.y;
    const int   f = face[idx];

    int x0 = (int)floorf(u);
    int y0 = (int)floorf(v);
    x0 = min(max(x0, 0), CUBE_LEN - 2);     // 0..510
    y0 = min(max(y0, 0), CUBE_LEN - 2);

    const float wx = u - (float)x0;         // in [0,1]
    const float wy = v - (float)y0;

    // per-lane byte offset inside the face-f block: face + row + col
    const uint32_t vb = (uint32_t)(f * 3145728 + y0 * (CUBE_LEN * 4) + x0 * 4);
    const uint64_t xb = (uint64_t)x;

    // uniform (e,c) byte offsets -> SGPR bases (3145728 B per face-image,
    // 18874368 B per equirect set, 1048576 B per channel plane)
#define ECB(e, c) ((uint64_t)((e) * 18874368u + (c) * 1048576u))

    // 12 images x {row0 pair, row1 pair}; all named scalars (SSA -> VGPRs)
    f32x2 ta0, tb0, ta1, tb1, ta2,  tb2,  ta3,  tb3,
          ta4, tb4, ta5, tb5, ta6,  tb6,  ta7,  tb7,
          ta8, tb8, ta9, tb9, ta10, tb10, ta11, tb11;

    asm volatile(
        "global_load_dwordx2 %[a0],  %[vb], %[s0]\n\t"
        "global_load_dwordx2 %[b0],  %[vb], %[s0] offset:2048\n\t"
        "global_load_dwordx2 %[a1],  %[vb], %[s1]\n\t"
        "global_load_dwordx2 %[b1],  %[vb], %[s1] offset:2048\n\t"
        "global_load_dwordx2 %[a2],  %[vb], %[s2]\n\t"
        "global_load_dwordx2 %[b2],  %[vb], %[s2] offset:2048\n\t"
        "global_load_dwordx2 %[a3],  %[vb], %[s3]\n\t"
        "global_load_dwordx2 %[b3],  %[vb], %[s3] offset:2048\n\t"
        "global_load_dwordx2 %[a4],  %[vb], %[s4]\n\t"
        "global_load_dwordx2 %[b4],  %[vb], %[s4] offset:2048\n\t"
        "global_load_dwordx2 %[a5],  %[vb], %[s5]\n\t"
        "global_load_dwordx2 %[b5],  %[vb], %[s5] offset:2048\n\t"
        "global_load_dwordx2 %[a6],  %[vb], %[s6]\n\t"
        "global_load_dwordx2 %[b6],  %[vb], %[s6] offset:2048\n\t"
        "global_load_dwordx2 %[a7],  %[vb], %[s7]\n\t"
        "global_load_dwordx2 %[b7],  %[vb], %[s7] offset:2048\n\t"
        "global_load_dwordx2 %[a8],  %[vb], %[s8]\n\t"
        "global_load_dwordx2 %[b8],  %[vb], %[s8] offset:2048\n\t"
        "global_load_dwordx2 %[a9],  %[vb], %[s9]\n\t"
        "global_load_dwordx2 %[b9],  %[vb], %[s9] offset:2048\n\t"
        "global_load_dwordx2 %[a10], %[vb], %[s10]\n\t"
        "global_load_dwordx2 %[b10], %[vb], %[s10] offset:2048\n\t"
        "global_load_dwordx2 %[a11], %[vb], %[s11]\n\t"
        "global_load_dwordx2 %[b11], %[vb], %[s11] offset:2048\n\t"
        "s_waitcnt vmcnt(0)"
        : [a0] "=&v"(ta0),  [b0] "=&v"(tb0),
          [a1] "=&v"(ta1),  [b1] "=&v"(tb1),
          [a2] "=&v"(ta2),  [b2] "=&v"(tb2),
          [a3] "=&v"(ta3),  [b3] "=&v"(tb3),
          [a4] "=&v"(ta4),  [b4] "=&v"(tb4),
          [a5] "=&v"(ta5),  [b5] "=&v"(tb5),
          [a6] "=&v"(ta6),  [b6] "=&v"(tb6),
          [a7] "=&v"(ta7),  [b7] "=&v"(tb7),
          [a8] "=&v"(ta8),  [b8] "=&v"(tb8),
          [a9] "=&v"(ta9),  [b9] "=&v"(tb9),
          [a10] "=&v"(ta10), [b10] "=&v"(tb10),
          [a11] "=&v"(ta11), [b11] "=&v"(tb11)
        : [vb] "v"(vb),
          [s0]  "s"(xb + ECB(0, 0)), [s1]  "s"(xb + ECB(0, 1)),
          [s2]  "s"(xb + ECB(0, 2)), [s3]  "s"(xb + ECB(1, 0)),
          [s4]  "s"(xb + ECB(1, 1)), [s5]  "s"(xb + ECB(1, 2)),
          [s6]  "s"(xb + ECB(2, 0)), [s7]  "s"(xb + ECB(2, 1)),
          [s8]  "s"(xb + ECB(2, 2)), [s9]  "s"(xb + ECB(3, 0)),
          [s10] "s"(xb + ECB(3, 1)), [s11] "s"(xb + ECB(3, 2)));

    // ---- compute + store (results already waited inside the asm) ----
    const float w00 = (1.0f - wx) * (1.0f - wy);
    const float w01 = wx * (1.0f - wy);
    const float w10 = (1.0f - wx) * wy;
    const float w11 = wx * wy;

#define EMIT(i, A, B)                                                        \
    {                                                                        \
        const float val = A.x * w00 + A.y * w01 + B.x * w10 + B.y * w11;     \
        __builtin_nontemporal_store(val, &out[(i) * HW + idx]);              \
    }

    EMIT(0,  ta0,  tb0)
    EMIT(1,  ta1,  tb1)
    EMIT(2,  ta2,  tb2)
    EMIT(3,  ta3,  tb3)
    EMIT(4,  ta4,  tb4)
    EMIT(5,  ta5,  tb5)
    EMIT(6,  ta6,  tb6)
    EMIT(7,  ta7,  tb7)
    EMIT(8,  ta8,  tb8)
    EMIT(9,  ta9,  tb9)
    EMIT(10, ta10, tb10)
    EMIT(11, ta11, tb11)
}

extern "C" void kernel_launch(void* const* d_in, const int* in_sizes, int n_in,
                              void* d_out, int out_size, void* d_ws, size_t ws_size,
                              hipStream_t stream) {
    const float* x    = (const float*)d_in[0];
    const float* uv   = (const float*)d_in[1];
    const int*   face = (const int*)d_in[2];
    float*       out  = (float*)d_out;

    const int HW = EQU_H * EQU_W;
    const int block = 256;
    const int grid  = (HW + block - 1) / block;  // 8192 blocks (8192 % 8 == 0)

    hipLaunchKernelGGL(cube2equirec_kernel, dim3(grid), dim3(block), 0, stream,
                       x, uv, face, out);
}

// Round 4
// 218.846 us; speedup vs baseline: 1.1006x; 1.1006x over previous
//
#include <hip/hip_runtime.h>
#include <stdint.h>

#define CUBE_LEN   512
#define EQU_H      1024
#define EQU_W      2048
#define EQU_COUNT  4
#define CHANNELS   3

typedef float f32x2 __attribute__((ext_vector_type(2)));

// One thread per equirect pixel. Bilinear taps re-parameterized so
// x1 = x0+1, y1 = y0+1 always: the 4 taps of each (e,c) image are two
// ADJACENT float pairs, rows 2048 bytes apart -> 2x global_load_dwordx2
// with imm offset 0 / 2048 per image. All 24 loads + the single
// s_waitcnt live in ONE asm block (round-8: named scalar SSA outputs,
// SGPR image bases) so the full batch is in flight per wave.
//
// Round-10: band swizzle REVERTED (118us vs 90us: pole/equator chunks
// imbalance -> tail; natural round-robin already maps vertical row
// neighbors to the same XCD since 8 blocks/row). New theory: 90us floor
// is TA line-request serialization - a wave's 64 lanes walking a 1-D
// equirect row segment trace a curve in cube space that crosses ~30-64
// cache lines per gather near the poles (row ~= circle on top face).
// Fix: 2-D thread tiling. Block = 16x16 pixel tile; each wave = 16-wide
// x 4-high patch -> compact cube-space blob -> fewer line splits per
// instruction. Stores/uv/face splits unchanged by construction (16x4B =
// 64B aligned row segments).
__global__ __launch_bounds__(256, 1) void cube2equirec_kernel(
    const float* __restrict__ x,
    const float* __restrict__ uv,
    const int*   __restrict__ face,
    float*       __restrict__ out)
{
    const int HW = EQU_H * EQU_W;           // 1 << 21

    // ---- 2-D tiling: 128 x 64 tiles of 16x16 pixels ----
    const int tx = threadIdx.x & 15;
    const int ty = threadIdx.x >> 4;
    const int bx = blockIdx.x & 127;        // 2048/16 = 128 tiles across
    const int by = blockIdx.x >> 7;         // 1024/16 = 64 tiles down
    const int w  = bx * 16 + tx;
    const int h  = by * 16 + ty;
    const int idx = h * EQU_W + w;          // in-range by construction

    const float2 uvv = ((const float2*)uv)[idx];
    const float u = uvv.x;
    const float v = uvv.y;
    const int   f = face[idx];

    int x0 = (int)floorf(u);
    int y0 = (int)floorf(v);
    x0 = min(max(x0, 0), CUBE_LEN - 2);     // 0..510
    y0 = min(max(y0, 0), CUBE_LEN - 2);

    const float wx = u - (float)x0;         // in [0,1]
    const float wy = v - (float)y0;

    // per-lane byte offset inside the face-f block: face + row + col
    const uint32_t vb = (uint32_t)(f * 3145728 + y0 * (CUBE_LEN * 4) + x0 * 4);
    const uint64_t xb = (uint64_t)x;

    // uniform (e,c) byte offsets -> SGPR bases (3145728 B per face-image,
    // 18874368 B per equirect set, 1048576 B per channel plane)
#define ECB(e, c) ((uint64_t)((e) * 18874368u + (c) * 1048576u))

    // 12 images x {row0 pair, row1 pair}; all named scalars (SSA -> VGPRs)
    f32x2 ta0, tb0, ta1, tb1, ta2,  tb2,  ta3,  tb3,
          ta4, tb4, ta5, tb5, ta6,  tb6,  ta7,  tb7,
          ta8, tb8, ta9, tb9, ta10, tb10, ta11, tb11;

    asm volatile(
        "global_load_dwordx2 %[a0],  %[vb], %[s0]\n\t"
        "global_load_dwordx2 %[b0],  %[vb], %[s0] offset:2048\n\t"
        "global_load_dwordx2 %[a1],  %[vb], %[s1]\n\t"
        "global_load_dwordx2 %[b1],  %[vb], %[s1] offset:2048\n\t"
        "global_load_dwordx2 %[a2],  %[vb], %[s2]\n\t"
        "global_load_dwordx2 %[b2],  %[vb], %[s2] offset:2048\n\t"
        "global_load_dwordx2 %[a3],  %[vb], %[s3]\n\t"
        "global_load_dwordx2 %[b3],  %[vb], %[s3] offset:2048\n\t"
        "global_load_dwordx2 %[a4],  %[vb], %[s4]\n\t"
        "global_load_dwordx2 %[b4],  %[vb], %[s4] offset:2048\n\t"
        "global_load_dwordx2 %[a5],  %[vb], %[s5]\n\t"
        "global_load_dwordx2 %[b5],  %[vb], %[s5] offset:2048\n\t"
        "global_load_dwordx2 %[a6],  %[vb], %[s6]\n\t"
        "global_load_dwordx2 %[b6],  %[vb], %[s6] offset:2048\n\t"
        "global_load_dwordx2 %[a7],  %[vb], %[s7]\n\t"
        "global_load_dwordx2 %[b7],  %[vb], %[s7] offset:2048\n\t"
        "global_load_dwordx2 %[a8],  %[vb], %[s8]\n\t"
        "global_load_dwordx2 %[b8],  %[vb], %[s8] offset:2048\n\t"
        "global_load_dwordx2 %[a9],  %[vb], %[s9]\n\t"
        "global_load_dwordx2 %[b9],  %[vb], %[s9] offset:2048\n\t"
        "global_load_dwordx2 %[a10], %[vb], %[s10]\n\t"
        "global_load_dwordx2 %[b10], %[vb], %[s10] offset:2048\n\t"
        "global_load_dwordx2 %[a11], %[vb], %[s11]\n\t"
        "global_load_dwordx2 %[b11], %[vb], %[s11] offset:2048\n\t"
        "s_waitcnt vmcnt(0)"
        : [a0] "=&v"(ta0),  [b0] "=&v"(tb0),
          [a1] "=&v"(ta1),  [b1] "=&v"(tb1),
          [a2] "=&v"(ta2),  [b2] "=&v"(tb2),
          [a3] "=&v"(ta3),  [b3] "=&v"(tb3),
          [a4] "=&v"(ta4),  [b4] "=&v"(tb4),
          [a5] "=&v"(ta5),  [b5] "=&v"(tb5),
          [a6] "=&v"(ta6),  [b6] "=&v"(tb6),
          [a7] "=&v"(ta7),  [b7] "=&v"(tb7),
          [a8] "=&v"(ta8),  [b8] "=&v"(tb8),
          [a9] "=&v"(ta9),  [b9] "=&v"(tb9),
          [a10] "=&v"(ta10), [b10] "=&v"(tb10),
          [a11] "=&v"(ta11), [b11] "=&v"(tb11)
        : [vb] "v"(vb),
          [s0]  "s"(xb + ECB(0, 0)), [s1]  "s"(xb + ECB(0, 1)),
          [s2]  "s"(xb + ECB(0, 2)), [s3]  "s"(xb + ECB(1, 0)),
          [s4]  "s"(xb + ECB(1, 1)), [s5]  "s"(xb + ECB(1, 2)),
          [s6]  "s"(xb + ECB(2, 0)), [s7]  "s"(xb + ECB(2, 1)),
          [s8]  "s"(xb + ECB(2, 2)), [s9]  "s"(xb + ECB(3, 0)),
          [s10] "s"(xb + ECB(3, 1)), [s11] "s"(xb + ECB(3, 2)));

    // ---- compute + store (results already waited inside the asm) ----
    const float w00 = (1.0f - wx) * (1.0f - wy);
    const float w01 = wx * (1.0f - wy);
    const float w10 = (1.0f - wx) * wy;
    const float w11 = wx * wy;

#define EMIT(i, A, B)                                                        \
    {                                                                        \
        const float val = A.x * w00 + A.y * w01 + B.x * w10 + B.y * w11;     \
        __builtin_nontemporal_store(val, &out[(i) * HW + idx]);              \
    }

    EMIT(0,  ta0,  tb0)
    EMIT(1,  ta1,  tb1)
    EMIT(2,  ta2,  tb2)
    EMIT(3,  ta3,  tb3)
    EMIT(4,  ta4,  tb4)
    EMIT(5,  ta5,  tb5)
    EMIT(6,  ta6,  tb6)
    EMIT(7,  ta7,  tb7)
    EMIT(8,  ta8,  tb8)
    EMIT(9,  ta9,  tb9)
    EMIT(10, ta10, tb10)
    EMIT(11, ta11, tb11)
}

extern "C" void kernel_launch(void* const* d_in, const int* in_sizes, int n_in,
                              void* d_out, int out_size, void* d_ws, size_t ws_size,
                              hipStream_t stream) {
    const float* x    = (const float*)d_in[0];
    const float* uv   = (const float*)d_in[1];
    const int*   face = (const int*)d_in[2];
    float*       out  = (float*)d_out;

    const int grid = (EQU_W / 16) * (EQU_H / 16);  // 128 * 64 = 8192 blocks
    hipLaunchKernelGGL(cube2equirec_kernel, dim3(grid), dim3(256), 0, stream,
                       x, uv, face, out);
}